// Round 16
// baseline (64.472 us; speedup 1.0000x reference)
//
#include <hip/hip_runtime.h>
#include <math.h>

#define B_ 4
#define C_ 256
#define N_ 2048
#define H_ 4
#define D_ 64

typedef __attribute__((ext_vector_type(8))) short bf16x8;
typedef __attribute__((ext_vector_type(4))) float f32x4;

#define QSCALE 0.18033688011112042f   // log2(e)/8

__device__ __forceinline__ float fexp2(float x) {
#if __has_builtin(__builtin_amdgcn_exp2f)
    return __builtin_amdgcn_exp2f(x);
#else
    float r;
    asm("v_exp_f32 %0, %1\n\ts_nop 1" : "=v"(r) : "v"(x));
    return r;
#endif
}

__device__ __forceinline__ ushort f2bf(float x) {
    uint u = __float_as_uint(x);
    uint r = (u + 0x7fffu + ((u >> 16) & 1u)) >> 16;
    return (ushort)r;
}
__device__ __forceinline__ float bf2f(ushort u) {
    return __uint_as_float((uint)u << 16);
}
__device__ __forceinline__ uint4 pack8(const ushort* v) {
    uint4 r;
    r.x = (uint)v[0] | ((uint)v[1] << 16);
    r.y = (uint)v[2] | ((uint)v[3] << 16);
    r.z = (uint)v[4] | ((uint)v[5] << 16);
    r.w = (uint)v[6] | ((uint)v[7] << 16);
    return r;
}
__device__ __forceinline__ void glds16(const void* g, void* l) {
    __builtin_amdgcn_global_load_lds(
        (const __attribute__((address_space(1))) unsigned int*)g,
        (__attribute__((address_space(3))) unsigned int*)l, 16, 0, 0);
}

// ---------------------------------------------------------------------------
// pack_w (unchanged): W fp32 [o][c] -> bf16 MFMA A-fragment images.
// ---------------------------------------------------------------------------
__global__ __launch_bounds__(256) void pack_w(const float* __restrict__ w0,
                                              const float* __restrict__ w1,
                                              const float* __restrict__ w2,
                                              const float* __restrict__ w3,
                                              ushort* __restrict__ Whimg,
                                              ushort* __restrict__ Wlimg) {
    const int ws = blockIdx.x;
    const int ks = blockIdx.y;
    const float* W = ws == 0 ? w0 : ws == 1 ? w1 : ws == 2 ? w2 : w3;
    ushort* Hh = Whimg + ws * 65536;
    ushort* Hl = Wlimg + ws * 65536;
    const int o  = threadIdx.x;
    const int of = o >> 4;
    const int li = o & 15;

    float v[32];
#pragma unroll
    for (int q = 0; q < 8; ++q)
        *(float4*)&v[q * 4] = *(const float4*)&W[o * 256 + ks * 32 + q * 4];

#pragma unroll
    for (int g = 0; g < 4; ++g) {
        ushort hi[8], lo[8];
#pragma unroll
        for (int e = 0; e < 8; ++e) {
            const float x = v[g * 8 + e];
            hi[e] = f2bf(x);
            lo[e] = f2bf(x - bf2f(hi[e]));
        }
        const size_t dst = ((size_t)(ks * 16 + of) * 64 + (g * 16 + li)) * 8;
        *(uint4*)(Hh + dst) = pack8(hi);
        if (ws == 3) *(uint4*)(Hl + dst) = pack8(lo);
    }
}

// ---------------------------------------------------------------------------
// proj_fused v4 (unchanged from R10): BK=64, 4 pipelined steps.
// ---------------------------------------------------------------------------
__global__ __launch_bounds__(256) void proj_fused(const float* __restrict__ Xq,
                                                  const float* __restrict__ Xk,
                                                  const float* __restrict__ Xv,
                                                  const ushort* __restrict__ Whimg,
                                                  const float* __restrict__ bq,
                                                  const float* __restrict__ bk,
                                                  const float* __restrict__ bv,
                                                  ushort* __restrict__ Qb,
                                                  ushort* __restrict__ Kimg,
                                                  ushort* __restrict__ Vimg) {
    __shared__ float  Xf[2][2048];    // fp32 staging [c64][n32], linear, dbuf
    __shared__ ushort Xb[2][2048];    // bf16 frag tile [n32][c64], granule-XOR, dbuf
    __shared__ ushort Ls[32][264];    // epilogue bf16 tile [n][o]

    const int z   = blockIdx.z;       // sel*4+b
    const int sel = z >> 2, b = z & 3;
    const int nt  = blockIdx.x;       // n0 = nt*32
    const int n0  = nt * 32;
    const int tid  = threadIdx.x;
    const int wv   = tid >> 6;
    const int lane = tid & 63;
    const int li   = lane & 15;
    const int g    = lane >> 4;
    const int l7   = li & 7;

    const float* X = (sel == 0 ? Xq : sel == 1 ? Xk : Xv) + (size_t)b * C_ * N_;
    const ushort* Wh  = Whimg + sel * 65536;
    const float* bias = sel == 0 ? bq : sel == 1 ? bk : bv;

    const int st_row = wv * 16 + (lane >> 3);
    const int st_col = (lane & 7) * 4;

    const int cv_n  = tid & 31;
    const int cv_g  = tid >> 5;            // 0..7
    const int cv_c0 = cv_g * 8;
    const int cv_sl = (cv_g ^ (cv_n & 7)) * 8;

#define PSTAGE(buf, s_)                                                          \
    do {                                                                         \
        const float* p_ = X + (size_t)((s_) * 64 + st_row) * N_ + n0 + st_col;   \
        glds16(p_,          &Xf[buf][wv * 512]);                                 \
        glds16(p_ + 8 * N_, &Xf[buf][wv * 512 + 256]);                           \
    } while (0)

#define PCONV(dst, src)                                                          \
    do {                                                                         \
        ushort t_[8];                                                            \
        _Pragma("unroll")                                                        \
        for (int e = 0; e < 8; ++e)                                              \
            t_[e] = f2bf(Xf[src][(cv_c0 + e) * 32 + cv_n]);                      \
        *(uint4*)&Xb[dst][cv_n * 64 + cv_sl] = pack8(t_);                        \
    } while (0)

    PSTAGE(0, 0);
    __syncthreads();
    PSTAGE(1, 1);
    PCONV(0, 0);
    __syncthreads();

    const f32x4 zv = {0.f, 0.f, 0.f, 0.f};
    f32x4 acc[4][2] = {{zv, zv}, {zv, zv}, {zv, zv}, {zv, zv}};

    for (int st = 0; st < 4; ++st) {
        if (st + 2 < 4) PSTAGE(st & 1, st + 2);
        if (st + 1 < 4) PCONV((st + 1) & 1, (st + 1) & 1);

        bf16x8 xb[2][2];
#pragma unroll
        for (int nf = 0; nf < 2; ++nf)
#pragma unroll
            for (int ksub = 0; ksub < 2; ++ksub)
                xb[nf][ksub] = *(const bf16x8*)
                    &Xb[st & 1][(16 * nf + li) * 64 + 8 * (((ksub << 2) + g) ^ l7)];

        __builtin_amdgcn_s_setprio(1);
#pragma unroll
        for (int ksub = 0; ksub < 2; ++ksub) {
            const size_t ab = ((size_t)((2 * st + ksub) * 16 + wv * 4) * 64 + lane) * 8;
#pragma unroll
            for (int ot = 0; ot < 4; ++ot) {
                const bf16x8 ah = *(const bf16x8*)(Wh + ab + (size_t)ot * 512);
#pragma unroll
                for (int nf = 0; nf < 2; ++nf)
                    acc[ot][nf] = __builtin_amdgcn_mfma_f32_16x16x32_bf16(
                        ah, xb[nf][ksub], acc[ot][nf], 0, 0, 0);
            }
        }
        __builtin_amdgcn_s_setprio(0);
        __syncthreads();
    }

    const float scale = (sel == 0) ? QSCALE : 1.0f;
#pragma unroll
    for (int ot = 0; ot < 4; ++ot)
#pragma unroll
        for (int nf = 0; nf < 2; ++nf)
#pragma unroll
            for (int r = 0; r < 4; ++r) {
                const int o = wv * 64 + ot * 16 + g * 4 + r;
                Ls[nf * 16 + li][o] = f2bf((acc[ot][nf][r] + bias[o]) * scale);
            }
    __syncthreads();

    const int h  = tid >> 6;
    const int bh = b * 4 + h;
    if (sel == 0) {
#pragma unroll
        for (int r_ = 0; r_ < 4; ++r_) {
            const int gi = (tid & 63) + 64 * r_;
            const int n_l = gi >> 3, dr = gi & 7;
            ushort u[8];
#pragma unroll
            for (int e = 0; e < 8; ++e) u[e] = Ls[n_l][(dr * 8 + e) * 4 + h];
            *(uint4*)(Qb + (((size_t)bh * N_) + n0 + n_l) * 64 + dr * 8) = pack8(u);
        }
    } else if (sel == 1) {
#pragma unroll
        for (int r_ = 0; r_ < 4; ++r_) {
            const int gi = (tid & 63) + 64 * r_;
            const int n_l = gi >> 3, dr = gi & 7;
            ushort u[8];
#pragma unroll
            for (int e = 0; e < 8; ++e) u[e] = Ls[n_l][(dr * 8 + e) * 4 + h];
            const int jg    = n0 + n_l;
            const int j     = jg & 63;
            const int ktile = jg >> 6;
            *(uint4*)(Kimg + (((size_t)bh * 32 + ktile) << 12) + j * 64 +
                      ((dr * 8) ^ ((j & 7) << 3))) = pack8(u);
        }
    } else {
#pragma unroll
        for (int r_ = 0; r_ < 4; ++r_) {
            const int gi = (tid & 63) + 64 * r_;
            const int d = gi >> 2, jr = gi & 3;
            ushort u[8];
#pragma unroll
            for (int e = 0; e < 8; ++e) u[e] = Ls[jr * 8 + e][d * 4 + h];
            const int jbase = (nt & 1) * 32 + jr * 8;
            const int ktile = nt >> 1;
            *(uint4*)(Vimg + (((size_t)bh * 32 + ktile) << 12) + d * 64 +
                      (jbase ^ ((d & 7) << 3))) = pack8(u);
        }
    }
#undef PSTAGE
#undef PCONV
}

// ---------------------------------------------------------------------------
// attn_v10: 256 queries per block (4 waves x 64q, qg=4) -> grid 256, 1/CU.
// Each kf/vf b128 LDS read now feeds 4 MFMAs (was 2): per-CU LDS-pipe time
// drops ~15.4 -> ~10.2 us, balancing the 9.3 us MFMA floor. Per-jt-fused
// softmax keeps VGPR ~180. Fragment math / tile order / Opart layout
// bit-identical to attn_v7.
// ---------------------------------------------------------------------------
__global__ __launch_bounds__(256, 1) void attn_v10(const ushort* __restrict__ Qb,
                                                   const ushort* __restrict__ Kimg,
                                                   const ushort* __restrict__ Vimg,
                                                   float* __restrict__ Opart,
                                                   float* __restrict__ lpart) {
    __shared__ ushort SMEM[32768];   // K dbuf 16KB | V dbuf 16KB | P 4 x 8KB

    const int bid = blockIdx.x;
    const int L   = (bid & 7) * 32 + (bid >> 3);   // bijective 256
    const int qt  = L & 7;
    const int ps  = L >> 3;         // 0..31
    const int bh  = ps >> 1;
    const int s   = ps & 1;

    const int tid  = threadIdx.x;
    const int wv   = tid >> 6;
    const int lane = tid & 63;
    const int li   = lane & 15;
    const int g    = lane >> 4;
    const int l7   = li & 7;
    const int i0w  = qt * 256 + wv * 64;

    bf16x8 qf[4][2];
#pragma unroll
    for (int qg = 0; qg < 4; ++qg)
#pragma unroll
        for (int ks = 0; ks < 2; ++ks)
            qf[qg][ks] = *(const bf16x8*)(Qb + ((size_t)bh * N_ + i0w + qg * 16 + li) * 64 +
                                          ks * 32 + g * 8);

    const ushort* Kg = Kimg + ((size_t)bh << 17);
    const ushort* Vg = Vimg + ((size_t)bh << 17);
    ushort* Pw = SMEM + 16384 + wv * 4096;      // 8KB/wave (64q x 64j bf16)

    const f32x4 z = {0.f, 0.f, 0.f, 0.f};
    f32x4 accO[4][4] = {{z, z, z, z}, {z, z, z, z}, {z, z, z, z}, {z, z, z, z}};
    f32x4 accL[4] = {z, z, z, z};
    const bf16x8 ones = {16256, 16256, 16256, 16256, 16256, 16256, 16256, 16256};

    const int kt0 = s * 16, kt1 = kt0 + 16;

#define STAGE(buf, kt_)                                                          \
    do {                                                                         \
        const ushort* ksrc = Kg + ((size_t)(kt_) << 12) + wv * 1024 + lane * 8;  \
        const ushort* vsrc = Vg + ((size_t)(kt_) << 12) + wv * 1024 + lane * 8;  \
        glds16(ksrc,       SMEM + (buf) * 4096 + wv * 1024);                     \
        glds16(ksrc + 512, SMEM + (buf) * 4096 + wv * 1024 + 512);               \
        glds16(vsrc,       SMEM + 8192 + (buf) * 4096 + wv * 1024);              \
        glds16(vsrc + 512, SMEM + 8192 + (buf) * 4096 + wv * 1024 + 512);        \
    } while (0)

    STAGE(0, kt0);
    __syncthreads();

    int cur = 0;
    for (int kt = kt0; kt < kt1; ++kt) {
        if (kt + 1 < kt1) STAGE(cur ^ 1, kt + 1);

        const ushort* Kc = SMEM + cur * 4096;
        const ushort* Vc = SMEM + 8192 + cur * 4096;

        // ---- QK^T + max-free softmax, fused per jt (keeps sc to 4 f32x4)
#pragma unroll
        for (int jt = 0; jt < 4; ++jt) {
            const ushort* row = Kc + (16 * jt + li) * 64;
            const bf16x8 kf0 = *(const bf16x8*)(row + 8 * (g ^ l7));
            const bf16x8 kf1 = *(const bf16x8*)(row + 8 * ((4 + g) ^ l7));
            f32x4 sc[4];
            __builtin_amdgcn_s_setprio(1);
#pragma unroll
            for (int qg = 0; qg < 4; ++qg) {
                f32x4 a = z;
                a = __builtin_amdgcn_mfma_f32_16x16x32_bf16(kf0, qf[qg][0], a, 0, 0, 0);
                a = __builtin_amdgcn_mfma_f32_16x16x32_bf16(kf1, qf[qg][1], a, 0, 0, 0);
                sc[qg] = a;
            }
            __builtin_amdgcn_s_setprio(0);
#pragma unroll
            for (int qg = 0; qg < 4; ++qg) {
                const float p0 = fexp2(sc[qg][0]);
                const float p1 = fexp2(sc[qg][1]);
                const float p2 = fexp2(sc[qg][2]);
                const float p3 = fexp2(sc[qg][3]);
                const uint a01 = (__float_as_uint(p1) & 0xffff0000u) | (__float_as_uint(p0) >> 16);
                const uint a23 = (__float_as_uint(p3) & 0xffff0000u) | (__float_as_uint(p2) >> 16);
                const uint byteoff = (uint)((qg * 16 + li) * 128) +
                                     (((uint)(jt * 32 + g * 8)) ^ ((uint)l7 << 4));
                *(uint2*)((char*)Pw + byteoff) = make_uint2(a01, a23);
            }
        }

        bf16x8 pf[4][2];
#pragma unroll
        for (int qg = 0; qg < 4; ++qg)
#pragma unroll
            for (int ks = 0; ks < 2; ++ks)
                pf[qg][ks] = *(const bf16x8*)((char*)Pw + (qg * 16 + li) * 128 +
                                              16 * ((4 * ks + g) ^ l7));

        __builtin_amdgcn_s_setprio(1);
#pragma unroll
        for (int qg = 0; qg < 4; ++qg) {
            accL[qg] = __builtin_amdgcn_mfma_f32_16x16x32_bf16(ones, pf[qg][0], accL[qg], 0, 0, 0);
            accL[qg] = __builtin_amdgcn_mfma_f32_16x16x32_bf16(ones, pf[qg][1], accL[qg], 0, 0, 0);
        }

        // ---- PV
#pragma unroll
        for (int dt = 0; dt < 4; ++dt) {
            const ushort* row = Vc + (16 * dt + li) * 64;
            const bf16x8 vf0 = *(const bf16x8*)(row + 8 * (g ^ l7));
            const bf16x8 vf1 = *(const bf16x8*)(row + 8 * ((4 + g) ^ l7));
#pragma unroll
            for (int qg = 0; qg < 4; ++qg) {
                f32x4 a = accO[dt][qg];
                a = __builtin_amdgcn_mfma_f32_16x16x32_bf16(vf0, pf[qg][0], a, 0, 0, 0);
                a = __builtin_amdgcn_mfma_f32_16x16x32_bf16(vf1, pf[qg][1], a, 0, 0, 0);
                accO[dt][qg] = a;
            }
        }
        __builtin_amdgcn_s_setprio(0);

        __syncthreads();
        cur ^= 1;
    }
#undef STAGE

    // ---- epilogue: unnormalized O^T -> Opart[slot][q16][d64] (slot layout
    // matches conv_out: slot = (s*16+bh)*128 + global 16q-tile index)
    const int sbase = (s * 16 + bh) * 128 + qt * 16 + wv * 4;
#pragma unroll
    for (int qg = 0; qg < 4; ++qg) {
        const int slot = sbase + qg;
        float* Op = Opart + (size_t)slot * 1024;
#pragma unroll
        for (int dt = 0; dt < 4; ++dt)
            *(f32x4*)&Op[li * 64 + dt * 16 + g * 4] = accO[dt][qg];
        if (g == 0) lpart[slot * 16 + li] = accL[qg][0];
    }
}

// ---------------------------------------------------------------------------
// conv_out v3 (unchanged from R15): n=64 x o=128, 512 threads, grid 256.
// ---------------------------------------------------------------------------
__global__ __launch_bounds__(512) void conv_out(const float* __restrict__ Opart,
                                                const float* __restrict__ lpart,
                                                const ushort* __restrict__ Whimg,
                                                const ushort* __restrict__ Wlimg,
                                                const float* __restrict__ bm,
                                                float* __restrict__ out) {
    __shared__ ushort Bh[2048 * 8];   // 32KB: granule G = q*32 + cg, ^ (q&7)
    __shared__ ushort Bl[2048 * 8];   // 32KB
    __shared__ float Linv[4][64];

    const int bx  = blockIdx.x;        // 0..31  (n0 = bx*64)
    const int b   = blockIdx.y;        // 0..3
    const int oh  = blockIdx.z;        // 0..1   (o0 = oh*128)
    const int n0  = bx * 64;
    const int tid = threadIdx.x;       // 0..511

    if (tid < 256) {
        const int h = tid >> 6, q = tid & 63;
        const int gq = (n0 + q) >> 4;
        const int qi = q & 15;
        const int sl0 = (0 * 16 + b * 4 + h) * 128 + gq;
        const int sl1 = (1 * 16 + b * 4 + h) * 128 + gq;
        Linv[h][q] = 1.0f / (lpart[sl0 * 16 + qi] + lpart[sl1 * 16 + qi]);
    }
    __syncthreads();

#pragma unroll
    for (int it = 0; it < 4; ++it) {
        const int id = tid + 512 * it;     // 0..2047
        const int h  = id >> 9;
        const int q  = (id >> 3) & 63;
        const int d0 = (id & 7) * 8;
        const int gq = (n0 + q) >> 4;
        const int qi = q & 15;
        const size_t sl0 = (size_t)((0 * 16 + b * 4 + h) * 128 + gq);
        const size_t sl1 = (size_t)((1 * 16 + b * 4 + h) * 128 + gq);
        const f32x4 v0a = *(const f32x4*)&Opart[sl0 * 1024 + qi * 64 + d0];
        const f32x4 v0b = *(const f32x4*)&Opart[sl0 * 1024 + qi * 64 + d0 + 4];
        const f32x4 v1a = *(const f32x4*)&Opart[sl1 * 1024 + qi * 64 + d0];
        const f32x4 v1b = *(const f32x4*)&Opart[sl1 * 1024 + qi * 64 + d0 + 4];
        const float li_ = Linv[h][q];
#pragma unroll
        for (int e = 0; e < 8; ++e) {
            const int d = d0 + e;
            const float vv = ((e < 4 ? v0a[e & 3] : v0b[e & 3]) +
                              (e < 4 ? v1a[e & 3] : v1b[e & 3])) * li_;
            const ushort hi = f2bf(vv);
            const ushort lo = f2bf(vv - bf2f(hi));
            const int cg = d >> 1;
            const int eb = (d & 1) * 4 + h;
            const int Gp = (q * 32 + cg) ^ (q & 7);
            Bh[Gp * 8 + eb] = hi;
            Bl[Gp * 8 + eb] = lo;
        }
    }
    __syncthreads();

    const int wv = tid >> 6, lane = tid & 63, li = lane & 15, g = lane >> 4;
    const int of = oh * 8 + wv;            // global 16-o tile index (0..15)
    const ushort* Wh = Whimg + 3 * 65536;
    const ushort* Wl = Wlimg + 3 * 65536;
    const f32x4 zv = {0.f, 0.f, 0.f, 0.f};
    f32x4 acc[4] = {zv, zv, zv, zv};       // [nf]

    for (int ks = 0; ks < 8; ++ks) {
        const size_t abase = ((size_t)(ks * 16 + of) * 64 + lane) * 8;
        const bf16x8 ah = *(const bf16x8*)(Wh + abase);
        const bf16x8 al = *(const bf16x8*)(Wl + abase);
#pragma unroll
        for (int nf = 0; nf < 4; ++nf) {
            const int Gp = ((16 * nf + li) * 32 + ks * 4 + g) ^ (li & 7);
            const bf16x8 bh_ = *(const bf16x8*)(Bh + Gp * 8);
            const bf16x8 bl_ = *(const bf16x8*)(Bl + Gp * 8);
            f32x4 a = acc[nf];
            a = __builtin_amdgcn_mfma_f32_16x16x32_bf16(ah, bl_, a, 0, 0, 0);
            a = __builtin_amdgcn_mfma_f32_16x16x32_bf16(al, bh_, a, 0, 0, 0);
            a = __builtin_amdgcn_mfma_f32_16x16x32_bf16(ah, bh_, a, 0, 0, 0);
            acc[nf] = a;
        }
    }

#pragma unroll
    for (int nf = 0; nf < 4; ++nf)
#pragma unroll
        for (int r = 0; r < 4; ++r) {
            const int o = oh * 128 + wv * 16 + g * 4 + r;
            out[((size_t)(b * 256 + o)) * N_ + n0 + nf * 16 + li] = acc[nf][r] + bm[o];
        }
}

// ---------------------------------------------------------------------------
extern "C" void kernel_launch(void* const* d_in, const int* in_sizes, int n_in,
                              void* d_out, int out_size, void* d_ws, size_t ws_size,
                              hipStream_t stream) {
    const float* query = (const float*)d_in[0];
    const float* key   = (const float*)d_in[1];
    const float* value = (const float*)d_in[2];
    const float* wq = (const float*)d_in[3];
    const float* bq = (const float*)d_in[4];
    const float* wk = (const float*)d_in[5];
    const float* bk = (const float*)d_in[6];
    const float* wv = (const float*)d_in[7];
    const float* bv = (const float*)d_in[8];
    const float* wm = (const float*)d_in[9];
    const float* bm = (const float*)d_in[10];

    float* out = (float*)d_out;
    char*  ws  = (char*)d_ws;

    const size_t TEN = (size_t)B_ * C_ * N_;            // 2,097,152

    float*  Opart = (float*)ws;
    float*  lpart = (float*)(ws + (size_t)4096 * 1024 * 4);
    ushort* Qb    = (ushort*)(ws + (size_t)4096 * 1024 * 4 + 262144);
    ushort* Kimg  = Qb + TEN;
    ushort* Vimg  = Kimg + TEN;
    ushort* Whimg = Vimg + TEN;
    ushort* Wlimg = Whimg + 4 * 65536;

    pack_w<<<dim3(4, 8), dim3(256), 0, stream>>>(wq, wk, wv, wm, Whimg, Wlimg);
    proj_fused<<<dim3(64, 1, 12), dim3(256), 0, stream>>>(query, key, value,
                                                          Whimg, bq, bk, bv,
                                                          Qb, Kimg, Vimg);
    attn_v10<<<dim3(256), dim3(256), 0, stream>>>(Qb, Kimg, Vimg, Opart, lpart);
    conv_out<<<dim3(32, 4, 2), dim3(512), 0, stream>>>(Opart, lpart, Whimg, Wlimg, bm, out);
}

// Round 17
// 57.513 us; speedup vs baseline: 1.1210x; 1.1210x over previous
//
#include <hip/hip_runtime.h>
#include <math.h>

#define B_ 4
#define C_ 256
#define N_ 2048
#define H_ 4
#define D_ 64

typedef __attribute__((ext_vector_type(8))) short bf16x8;
typedef __attribute__((ext_vector_type(4))) float f32x4;

#define QSCALE 0.18033688011112042f   // log2(e)/8

__device__ __forceinline__ float fexp2(float x) {
#if __has_builtin(__builtin_amdgcn_exp2f)
    return __builtin_amdgcn_exp2f(x);
#else
    float r;
    asm("v_exp_f32 %0, %1\n\ts_nop 1" : "=v"(r) : "v"(x));
    return r;
#endif
}

__device__ __forceinline__ ushort f2bf(float x) {
    uint u = __float_as_uint(x);
    uint r = (u + 0x7fffu + ((u >> 16) & 1u)) >> 16;
    return (ushort)r;
}
__device__ __forceinline__ float bf2f(ushort u) {
    return __uint_as_float((uint)u << 16);
}
__device__ __forceinline__ uint4 pack8(const ushort* v) {
    uint4 r;
    r.x = (uint)v[0] | ((uint)v[1] << 16);
    r.y = (uint)v[2] | ((uint)v[3] << 16);
    r.z = (uint)v[4] | ((uint)v[5] << 16);
    r.w = (uint)v[6] | ((uint)v[7] << 16);
    return r;
}
__device__ __forceinline__ void glds16(const void* g, void* l) {
    __builtin_amdgcn_global_load_lds(
        (const __attribute__((address_space(1))) unsigned int*)g,
        (__attribute__((address_space(3))) unsigned int*)l, 16, 0, 0);
}

// ---------------------------------------------------------------------------
// pack_w (unchanged): W fp32 [o][c] -> bf16 MFMA A-fragment images.
// ---------------------------------------------------------------------------
__global__ __launch_bounds__(256) void pack_w(const float* __restrict__ w0,
                                              const float* __restrict__ w1,
                                              const float* __restrict__ w2,
                                              const float* __restrict__ w3,
                                              ushort* __restrict__ Whimg,
                                              ushort* __restrict__ Wlimg) {
    const int ws = blockIdx.x;
    const int ks = blockIdx.y;
    const float* W = ws == 0 ? w0 : ws == 1 ? w1 : ws == 2 ? w2 : w3;
    ushort* Hh = Whimg + ws * 65536;
    ushort* Hl = Wlimg + ws * 65536;
    const int o  = threadIdx.x;
    const int of = o >> 4;
    const int li = o & 15;

    float v[32];
#pragma unroll
    for (int q = 0; q < 8; ++q)
        *(float4*)&v[q * 4] = *(const float4*)&W[o * 256 + ks * 32 + q * 4];

#pragma unroll
    for (int g = 0; g < 4; ++g) {
        ushort hi[8], lo[8];
#pragma unroll
        for (int e = 0; e < 8; ++e) {
            const float x = v[g * 8 + e];
            hi[e] = f2bf(x);
            lo[e] = f2bf(x - bf2f(hi[e]));
        }
        const size_t dst = ((size_t)(ks * 16 + of) * 64 + (g * 16 + li)) * 8;
        *(uint4*)(Hh + dst) = pack8(hi);
        if (ws == 3) *(uint4*)(Hl + dst) = pack8(lo);
    }
}

// ---------------------------------------------------------------------------
// proj_fused v4 (unchanged from R10): BK=64, 4 pipelined steps.
// ---------------------------------------------------------------------------
__global__ __launch_bounds__(256) void proj_fused(const float* __restrict__ Xq,
                                                  const float* __restrict__ Xk,
                                                  const float* __restrict__ Xv,
                                                  const ushort* __restrict__ Whimg,
                                                  const float* __restrict__ bq,
                                                  const float* __restrict__ bk,
                                                  const float* __restrict__ bv,
                                                  ushort* __restrict__ Qb,
                                                  ushort* __restrict__ Kimg,
                                                  ushort* __restrict__ Vimg) {
    __shared__ float  Xf[2][2048];    // fp32 staging [c64][n32], linear, dbuf
    __shared__ ushort Xb[2][2048];    // bf16 frag tile [n32][c64], granule-XOR, dbuf
    __shared__ ushort Ls[32][264];    // epilogue bf16 tile [n][o]

    const int z   = blockIdx.z;       // sel*4+b
    const int sel = z >> 2, b = z & 3;
    const int nt  = blockIdx.x;       // n0 = nt*32
    const int n0  = nt * 32;
    const int tid  = threadIdx.x;
    const int wv   = tid >> 6;
    const int lane = tid & 63;
    const int li   = lane & 15;
    const int g    = lane >> 4;
    const int l7   = li & 7;

    const float* X = (sel == 0 ? Xq : sel == 1 ? Xk : Xv) + (size_t)b * C_ * N_;
    const ushort* Wh  = Whimg + sel * 65536;
    const float* bias = sel == 0 ? bq : sel == 1 ? bk : bv;

    const int st_row = wv * 16 + (lane >> 3);
    const int st_col = (lane & 7) * 4;

    const int cv_n  = tid & 31;
    const int cv_g  = tid >> 5;            // 0..7
    const int cv_c0 = cv_g * 8;
    const int cv_sl = (cv_g ^ (cv_n & 7)) * 8;

#define PSTAGE(buf, s_)                                                          \
    do {                                                                         \
        const float* p_ = X + (size_t)((s_) * 64 + st_row) * N_ + n0 + st_col;   \
        glds16(p_,          &Xf[buf][wv * 512]);                                 \
        glds16(p_ + 8 * N_, &Xf[buf][wv * 512 + 256]);                           \
    } while (0)

#define PCONV(dst, src)                                                          \
    do {                                                                         \
        ushort t_[8];                                                            \
        _Pragma("unroll")                                                        \
        for (int e = 0; e < 8; ++e)                                              \
            t_[e] = f2bf(Xf[src][(cv_c0 + e) * 32 + cv_n]);                      \
        *(uint4*)&Xb[dst][cv_n * 64 + cv_sl] = pack8(t_);                        \
    } while (0)

    PSTAGE(0, 0);
    __syncthreads();
    PSTAGE(1, 1);
    PCONV(0, 0);
    __syncthreads();

    const f32x4 zv = {0.f, 0.f, 0.f, 0.f};
    f32x4 acc[4][2] = {{zv, zv}, {zv, zv}, {zv, zv}, {zv, zv}};

    for (int st = 0; st < 4; ++st) {
        if (st + 2 < 4) PSTAGE(st & 1, st + 2);
        if (st + 1 < 4) PCONV((st + 1) & 1, (st + 1) & 1);

        bf16x8 xb[2][2];
#pragma unroll
        for (int nf = 0; nf < 2; ++nf)
#pragma unroll
            for (int ksub = 0; ksub < 2; ++ksub)
                xb[nf][ksub] = *(const bf16x8*)
                    &Xb[st & 1][(16 * nf + li) * 64 + 8 * (((ksub << 2) + g) ^ l7)];

        __builtin_amdgcn_s_setprio(1);
#pragma unroll
        for (int ksub = 0; ksub < 2; ++ksub) {
            const size_t ab = ((size_t)((2 * st + ksub) * 16 + wv * 4) * 64 + lane) * 8;
#pragma unroll
            for (int ot = 0; ot < 4; ++ot) {
                const bf16x8 ah = *(const bf16x8*)(Wh + ab + (size_t)ot * 512);
#pragma unroll
                for (int nf = 0; nf < 2; ++nf)
                    acc[ot][nf] = __builtin_amdgcn_mfma_f32_16x16x32_bf16(
                        ah, xb[nf][ksub], acc[ot][nf], 0, 0, 0);
            }
        }
        __builtin_amdgcn_s_setprio(0);
        __syncthreads();
    }

    const float scale = (sel == 0) ? QSCALE : 1.0f;
#pragma unroll
    for (int ot = 0; ot < 4; ++ot)
#pragma unroll
        for (int nf = 0; nf < 2; ++nf)
#pragma unroll
            for (int r = 0; r < 4; ++r) {
                const int o = wv * 64 + ot * 16 + g * 4 + r;
                Ls[nf * 16 + li][o] = f2bf((acc[ot][nf][r] + bias[o]) * scale);
            }
    __syncthreads();

    const int h  = tid >> 6;
    const int bh = b * 4 + h;
    if (sel == 0) {
#pragma unroll
        for (int r_ = 0; r_ < 4; ++r_) {
            const int gi = (tid & 63) + 64 * r_;
            const int n_l = gi >> 3, dr = gi & 7;
            ushort u[8];
#pragma unroll
            for (int e = 0; e < 8; ++e) u[e] = Ls[n_l][(dr * 8 + e) * 4 + h];
            *(uint4*)(Qb + (((size_t)bh * N_) + n0 + n_l) * 64 + dr * 8) = pack8(u);
        }
    } else if (sel == 1) {
#pragma unroll
        for (int r_ = 0; r_ < 4; ++r_) {
            const int gi = (tid & 63) + 64 * r_;
            const int n_l = gi >> 3, dr = gi & 7;
            ushort u[8];
#pragma unroll
            for (int e = 0; e < 8; ++e) u[e] = Ls[n_l][(dr * 8 + e) * 4 + h];
            const int jg    = n0 + n_l;
            const int j     = jg & 63;
            const int ktile = jg >> 6;
            *(uint4*)(Kimg + (((size_t)bh * 32 + ktile) << 12) + j * 64 +
                      ((dr * 8) ^ ((j & 7) << 3))) = pack8(u);
        }
    } else {
#pragma unroll
        for (int r_ = 0; r_ < 4; ++r_) {
            const int gi = (tid & 63) + 64 * r_;
            const int d = gi >> 2, jr = gi & 3;
            ushort u[8];
#pragma unroll
            for (int e = 0; e < 8; ++e) u[e] = Ls[jr * 8 + e][d * 4 + h];
            const int jbase = (nt & 1) * 32 + jr * 8;
            const int ktile = nt >> 1;
            *(uint4*)(Vimg + (((size_t)bh * 32 + ktile) << 12) + d * 64 +
                      (jbase ^ ((d & 7) << 3))) = pack8(u);
        }
    }
#undef PSTAGE
#undef PCONV
}

// ---------------------------------------------------------------------------
// attn_v11: attn_v7 per-wave shape (qg=2, 32q/wave) but 512-thread blocks
// (8 waves, 256 q/block), grid 256 = 1 block/CU x 8 waves = 2 waves/SIMD
// (same TLP as R15). K/V staging shared by 8 waves: glds/L2 traffic halves
// (134 -> 67 MB). Per-lane fragment math and Opart layout bit-identical.
// ---------------------------------------------------------------------------
__global__ __launch_bounds__(512) void attn_v11(const ushort* __restrict__ Qb,
                                                const ushort* __restrict__ Kimg,
                                                const ushort* __restrict__ Vimg,
                                                float* __restrict__ Opart,
                                                float* __restrict__ lpart) {
    __shared__ ushort SMEM[32768];   // K dbuf 16KB | V dbuf 16KB | P 8 x 4KB

    const int bid = blockIdx.x;
    const int L   = (bid & 7) * 32 + (bid >> 3);   // bijective 256
    const int qt  = L & 7;          // 256-q tile
    const int ps  = L >> 3;         // 0..31
    const int bh  = ps >> 1;
    const int s   = ps & 1;

    const int tid  = threadIdx.x;   // 0..511
    const int wv   = tid >> 6;      // 0..7
    const int lane = tid & 63;
    const int li   = lane & 15;
    const int g    = lane >> 4;
    const int l7   = li & 7;
    const int i0w  = qt * 256 + wv * 32;

    bf16x8 qf[2][2];
#pragma unroll
    for (int qg = 0; qg < 2; ++qg)
#pragma unroll
        for (int ks = 0; ks < 2; ++ks)
            qf[qg][ks] = *(const bf16x8*)(Qb + ((size_t)bh * N_ + i0w + qg * 16 + li) * 64 +
                                          ks * 32 + g * 8);

    const ushort* Kg = Kimg + ((size_t)bh << 17);
    const ushort* Vg = Vimg + ((size_t)bh << 17);
    ushort* Pw = SMEM + 16384 + wv * 2048;      // 4KB/wave (32q x 64j bf16)

    const f32x4 z = {0.f, 0.f, 0.f, 0.f};
    f32x4 accO[4][2] = {{z, z}, {z, z}, {z, z}, {z, z}};
    f32x4 accL[2] = {z, z};
    const bf16x8 ones = {16256, 16256, 16256, 16256, 16256, 16256, 16256, 16256};

    const int kt0 = s * 16, kt1 = kt0 + 16;

    // 8 waves: each stages 512 ushorts of K and 512 of V (1 glds16 each)
#define STAGE(buf, kt_)                                                          \
    do {                                                                         \
        const ushort* ksrc = Kg + ((size_t)(kt_) << 12) + wv * 512 + lane * 8;   \
        const ushort* vsrc = Vg + ((size_t)(kt_) << 12) + wv * 512 + lane * 8;   \
        glds16(ksrc, SMEM + (buf) * 4096 + wv * 512);                            \
        glds16(vsrc, SMEM + 8192 + (buf) * 4096 + wv * 512);                     \
    } while (0)

    STAGE(0, kt0);
    __syncthreads();

    int cur = 0;
    for (int kt = kt0; kt < kt1; ++kt) {
        if (kt + 1 < kt1) STAGE(cur ^ 1, kt + 1);

        const ushort* Kc = SMEM + cur * 4096;
        const ushort* Vc = SMEM + 8192 + cur * 4096;

        // ---- QK^T: lane holds S^T[j=16jt+4g+r][q = qg*16+li]
        f32x4 sc[4][2];
        __builtin_amdgcn_s_setprio(1);
#pragma unroll
        for (int jt = 0; jt < 4; ++jt) {
            const ushort* row = Kc + (16 * jt + li) * 64;
            const bf16x8 kf0 = *(const bf16x8*)(row + 8 * (g ^ l7));
            const bf16x8 kf1 = *(const bf16x8*)(row + 8 * ((4 + g) ^ l7));
#pragma unroll
            for (int qg = 0; qg < 2; ++qg) {
                f32x4 a = z;
                a = __builtin_amdgcn_mfma_f32_16x16x32_bf16(kf0, qf[qg][0], a, 0, 0, 0);
                a = __builtin_amdgcn_mfma_f32_16x16x32_bf16(kf1, qf[qg][1], a, 0, 0, 0);
                sc[jt][qg] = a;
            }
        }
        __builtin_amdgcn_s_setprio(0);

        // ---- max-free softmax: p = exp2(s), write P^T to wave-private LDS
#pragma unroll
        for (int qg = 0; qg < 2; ++qg) {
            const uint rowb = (uint)((qg * 16 + li) * 128);
#pragma unroll
            for (int jt = 0; jt < 4; ++jt) {
                const float p0 = fexp2(sc[jt][qg][0]);
                const float p1 = fexp2(sc[jt][qg][1]);
                const float p2 = fexp2(sc[jt][qg][2]);
                const float p3 = fexp2(sc[jt][qg][3]);
                const uint a01 = (__float_as_uint(p1) & 0xffff0000u) | (__float_as_uint(p0) >> 16);
                const uint a23 = (__float_as_uint(p3) & 0xffff0000u) | (__float_as_uint(p2) >> 16);
                const uint byteoff = rowb + (((uint)(jt * 32 + g * 8)) ^ ((uint)l7 << 4));
                *(uint2*)((char*)Pw + byteoff) = make_uint2(a01, a23);
            }
        }

        bf16x8 pf[2][2];
#pragma unroll
        for (int qg = 0; qg < 2; ++qg)
#pragma unroll
            for (int ks = 0; ks < 2; ++ks)
                pf[qg][ks] = *(const bf16x8*)((char*)Pw + (qg * 16 + li) * 128 +
                                              16 * ((4 * ks + g) ^ l7));

        __builtin_amdgcn_s_setprio(1);
#pragma unroll
        for (int qg = 0; qg < 2; ++qg) {
            accL[qg] = __builtin_amdgcn_mfma_f32_16x16x32_bf16(ones, pf[qg][0], accL[qg], 0, 0, 0);
            accL[qg] = __builtin_amdgcn_mfma_f32_16x16x32_bf16(ones, pf[qg][1], accL[qg], 0, 0, 0);
        }

        // ---- PV
#pragma unroll
        for (int dt = 0; dt < 4; ++dt) {
            const ushort* row = Vc + (16 * dt + li) * 64;
            const bf16x8 vf0 = *(const bf16x8*)(row + 8 * (g ^ l7));
            const bf16x8 vf1 = *(const bf16x8*)(row + 8 * ((4 + g) ^ l7));
#pragma unroll
            for (int qg = 0; qg < 2; ++qg) {
                f32x4 a = accO[dt][qg];
                a = __builtin_amdgcn_mfma_f32_16x16x32_bf16(vf0, pf[qg][0], a, 0, 0, 0);
                a = __builtin_amdgcn_mfma_f32_16x16x32_bf16(vf1, pf[qg][1], a, 0, 0, 0);
                accO[dt][qg] = a;
            }
        }
        __builtin_amdgcn_s_setprio(0);

        __syncthreads();
        cur ^= 1;
    }
#undef STAGE

    // ---- epilogue: slot = (s*16+bh)*128 + qt*16 + wv*2 + qg  (0..127 per
    // split+bh, matches conv_out layout exactly)
    const int sbase = (s * 16 + bh) * 128 + qt * 16 + wv * 2;
#pragma unroll
    for (int qg = 0; qg < 2; ++qg) {
        const int slot = sbase + qg;
        float* Op = Opart + (size_t)slot * 1024;
#pragma unroll
        for (int dt = 0; dt < 4; ++dt)
            *(f32x4*)&Op[li * 64 + dt * 16 + g * 4] = accO[dt][qg];
        if (g == 0) lpart[slot * 16 + li] = accL[qg][0];
    }
}

// ---------------------------------------------------------------------------
// conv_out v3 (unchanged from R15): n=64 x o=128, 512 threads, grid 256.
// ---------------------------------------------------------------------------
__global__ __launch_bounds__(512) void conv_out(const float* __restrict__ Opart,
                                                const float* __restrict__ lpart,
                                                const ushort* __restrict__ Whimg,
                                                const ushort* __restrict__ Wlimg,
                                                const float* __restrict__ bm,
                                                float* __restrict__ out) {
    __shared__ ushort Bh[2048 * 8];   // 32KB
    __shared__ ushort Bl[2048 * 8];   // 32KB
    __shared__ float Linv[4][64];

    const int bx  = blockIdx.x;        // 0..31  (n0 = bx*64)
    const int b   = blockIdx.y;        // 0..3
    const int oh  = blockIdx.z;        // 0..1   (o0 = oh*128)
    const int n0  = bx * 64;
    const int tid = threadIdx.x;       // 0..511

    if (tid < 256) {
        const int h = tid >> 6, q = tid & 63;
        const int gq = (n0 + q) >> 4;
        const int qi = q & 15;
        const int sl0 = (0 * 16 + b * 4 + h) * 128 + gq;
        const int sl1 = (1 * 16 + b * 4 + h) * 128 + gq;
        Linv[h][q] = 1.0f / (lpart[sl0 * 16 + qi] + lpart[sl1 * 16 + qi]);
    }
    __syncthreads();

#pragma unroll
    for (int it = 0; it < 4; ++it) {
        const int id = tid + 512 * it;     // 0..2047
        const int h  = id >> 9;
        const int q  = (id >> 3) & 63;
        const int d0 = (id & 7) * 8;
        const int gq = (n0 + q) >> 4;
        const int qi = q & 15;
        const size_t sl0 = (size_t)((0 * 16 + b * 4 + h) * 128 + gq);
        const size_t sl1 = (size_t)((1 * 16 + b * 4 + h) * 128 + gq);
        const f32x4 v0a = *(const f32x4*)&Opart[sl0 * 1024 + qi * 64 + d0];
        const f32x4 v0b = *(const f32x4*)&Opart[sl0 * 1024 + qi * 64 + d0 + 4];
        const f32x4 v1a = *(const f32x4*)&Opart[sl1 * 1024 + qi * 64 + d0];
        const f32x4 v1b = *(const f32x4*)&Opart[sl1 * 1024 + qi * 64 + d0 + 4];
        const float li_ = Linv[h][q];
#pragma unroll
        for (int e = 0; e < 8; ++e) {
            const int d = d0 + e;
            const float vv = ((e < 4 ? v0a[e & 3] : v0b[e & 3]) +
                              (e < 4 ? v1a[e & 3] : v1b[e & 3])) * li_;
            const ushort hi = f2bf(vv);
            const ushort lo = f2bf(vv - bf2f(hi));
            const int cg = d >> 1;
            const int eb = (d & 1) * 4 + h;
            const int Gp = (q * 32 + cg) ^ (q & 7);
            Bh[Gp * 8 + eb] = hi;
            Bl[Gp * 8 + eb] = lo;
        }
    }
    __syncthreads();

    const int wv = tid >> 6, lane = tid & 63, li = lane & 15, g = lane >> 4;
    const int of = oh * 8 + wv;
    const ushort* Wh = Whimg + 3 * 65536;
    const ushort* Wl = Wlimg + 3 * 65536;
    const f32x4 zv = {0.f, 0.f, 0.f, 0.f};
    f32x4 acc[4] = {zv, zv, zv, zv};

    for (int ks = 0; ks < 8; ++ks) {
        const size_t abase = ((size_t)(ks * 16 + of) * 64 + lane) * 8;
        const bf16x8 ah = *(const bf16x8*)(Wh + abase);
        const bf16x8 al = *(const bf16x8*)(Wl + abase);
#pragma unroll
        for (int nf = 0; nf < 4; ++nf) {
            const int Gp = ((16 * nf + li) * 32 + ks * 4 + g) ^ (li & 7);
            const bf16x8 bh_ = *(const bf16x8*)(Bh + Gp * 8);
            const bf16x8 bl_ = *(const bf16x8*)(Bl + Gp * 8);
            f32x4 a = acc[nf];
            a = __builtin_amdgcn_mfma_f32_16x16x32_bf16(ah, bl_, a, 0, 0, 0);
            a = __builtin_amdgcn_mfma_f32_16x16x32_bf16(al, bh_, a, 0, 0, 0);
            a = __builtin_amdgcn_mfma_f32_16x16x32_bf16(ah, bh_, a, 0, 0, 0);
            acc[nf] = a;
        }
    }

#pragma unroll
    for (int nf = 0; nf < 4; ++nf)
#pragma unroll
        for (int r = 0; r < 4; ++r) {
            const int o = oh * 128 + wv * 16 + g * 4 + r;
            out[((size_t)(b * 256 + o)) * N_ + n0 + nf * 16 + li] = acc[nf][r] + bm[o];
        }
}

// ---------------------------------------------------------------------------
extern "C" void kernel_launch(void* const* d_in, const int* in_sizes, int n_in,
                              void* d_out, int out_size, void* d_ws, size_t ws_size,
                              hipStream_t stream) {
    const float* query = (const float*)d_in[0];
    const float* key   = (const float*)d_in[1];
    const float* value = (const float*)d_in[2];
    const float* wq = (const float*)d_in[3];
    const float* bq = (const float*)d_in[4];
    const float* wk = (const float*)d_in[5];
    const float* bk = (const float*)d_in[6];
    const float* wv = (const float*)d_in[7];
    const float* bv = (const float*)d_in[8];
    const float* wm = (const float*)d_in[9];
    const float* bm = (const float*)d_in[10];

    float* out = (float*)d_out;
    char*  ws  = (char*)d_ws;

    const size_t TEN = (size_t)B_ * C_ * N_;            // 2,097,152

    float*  Opart = (float*)ws;
    float*  lpart = (float*)(ws + (size_t)4096 * 1024 * 4);
    ushort* Qb    = (ushort*)(ws + (size_t)4096 * 1024 * 4 + 262144);
    ushort* Kimg  = Qb + TEN;
    ushort* Vimg  = Kimg + TEN;
    ushort* Whimg = Vimg + TEN;
    ushort* Wlimg = Whimg + 4 * 65536;

    pack_w<<<dim3(4, 8), dim3(256), 0, stream>>>(wq, wk, wv, wm, Whimg, Wlimg);
    proj_fused<<<dim3(64, 1, 12), dim3(256), 0, stream>>>(query, key, value,
                                                          Whimg, bq, bk, bv,
                                                          Qb, Kimg, Vimg);
    attn_v11<<<dim3(256), dim3(512), 0, stream>>>(Qb, Kimg, Vimg, Opart, lpart);
    conv_out<<<dim3(32, 4, 2), dim3(512), 0, stream>>>(Opart, lpart, Whimg, Wlimg, bm, out);
}